// Round 2
// 360.413 us; speedup vs baseline: 1.0849x; 1.0849x over previous
//
#include <hip/hip_runtime.h>

// Problem constants (match reference)
#define PFN_NX     512
#define PFN_NY     512
#define PFN_P      (PFN_NX * PFN_NY)     // 262144 pillars (2^18)
#define PFN_B      4
#define PFN_NPTS   100000
#define PFN_C      64
#define PFN_NBIN   (PFN_B * PFN_P)       // 1,048,576 (b,pillar) bins
#define PFN_TOTPTS (PFN_B * PFN_NPTS)    // 400,000 points

typedef float f32x4 __attribute__((ext_vector_type(4)));  // native vec for nt-store

// Workspace layout (ints):
//   head [NBIN]    : per-(b,pillar) list head, -1 = empty  (memset 0xFF)
//   nxt  [TOTPTS]  : next-point link per point id
//
// R7: replace the 4-kernel counting sort (hist + block_reduce + scan +
// reorder, 2 atomics/point, scattered order[] writes, 2x 4MB scan traffic)
// with atomicExch linked-list chaining: ONE kernel, ONE atomic/point, and the
// nxt[] store is coalesced (nxt[pi] with pi = global thread id). The gather
// walks the 16 lists of its wave concurrently: one point per live bin per
// round, every round issuing up to 16 INDEPENDENT x-row loads, with the
// nxt[] pointer loads issued FIRST so their latency hides under the x
// processing. Expected rounds/wave ~2-3 (Poisson occupancy 0.38, 16 bins).

__global__ __launch_bounds__(256) void pfn_build(const int* __restrict__ idx,
                                                 int* __restrict__ head,
                                                 int* __restrict__ nxt) {
    int pi = blockIdx.x * 256 + threadIdx.x;
    if (pi >= PFN_TOTPTS) return;
    int b  = (unsigned)pi / PFN_NPTS;
    int bp = b * PFN_P + idx[pi];
    nxt[pi] = atomicExch(&head[bp], pi);   // coalesced store + 1 atomic/point
}

// ---------------------------------------------------------------------------
// Gather: one workgroup per 64 consecutive bins; wave owns 16 bins,
// lane = channel for the accumulate phase (256 B coalesced x reads).
// LDS tile is [channel][local pillar] with +1 pad (bank = (lane+col)%32 for
// the RMW -> 2-way only, free). Epilogue writes float4 (256 B per 16-lane
// channel row), nontemporal: the 256 MB output is never re-read, keep it out
// of L2/LLC so x (102 MB) and nxt stay resident.
// ---------------------------------------------------------------------------
__global__ __launch_bounds__(256) void pfn_gather(const float* __restrict__ x,
                                                  const int*   __restrict__ head,
                                                  const int*   __restrict__ nxt,
                                                  float*       __restrict__ out) {
    __shared__ float tile[64][65];       // [channel][local pillar], +1 pad
    const int g    = blockIdx.x;         // [0, NBIN/64)
    const int bp0  = g << 6;
    const int b    = bp0 >> 18;          // / P
    const int p0   = bp0 & (PFN_P - 1);
    const int wave = threadIdx.x >> 6;
    const int lane = threadIdx.x & 63;
    const int wb0  = bp0 + wave * 16;    // this wave's first bin

    // lane j < 16 walks the list of bin wb0+j
    int cur = -1;
    if (lane < 16) cur = head[wb0 + lane];

    // zero this wave's 16 columns (2-way banks, free)
#pragma unroll
    for (int k = 0; k < 16; ++k) tile[lane][wave * 16 + k] = 0.f;

    unsigned long long m;
    while ((m = __ballot(cur >= 0)) != 0ull) {
        // issue next-pointer loads FIRST; latency hides under x processing
        int nxtv = -1;
        if (cur >= 0) nxtv = nxt[cur];

        // up to 16 independent x-row loads (static reg indices — no scratch)
        float pre[16];
#pragma unroll
        for (int j = 0; j < 16; ++j) {
            if ((m >> j) & 1ull) {                  // wave-uniform branch
                const int pi = __shfl(cur, j);      // broadcast bin j's point
                pre[j] = x[((size_t)pi << 6) + lane];
            }
        }
        // short LDS RMWs into the wave's own 16 columns (race-free ownership)
#pragma unroll
        for (int j = 0; j < 16; ++j) {
            if ((m >> j) & 1ull) tile[lane][wave * 16 + j] += pre[j];
        }
        cur = nxtv;
    }
    __syncthreads();

    // epilogue: 1024 float4 stores, 4 per thread; 16 lanes cover one channel
    // row (256 B contiguous), 4 channels per wave per iteration.
    const size_t outBase = (size_t)b << 24;          // b * 64 * P
#pragma unroll
    for (int k = 0; k < 4; ++k) {
        const int id = k * 256 + threadIdx.x;        // [0, 1024)
        const int c  = id >> 4;                      // channel
        const int i  = id & 15;                      // float4 index in p
        f32x4 v;
        v.x = tile[c][4 * i + 0];
        v.y = tile[c][4 * i + 1];
        v.z = tile[c][4 * i + 2];
        v.w = tile[c][4 * i + 3];
        __builtin_nontemporal_store(
            v, (f32x4*)(out + outBase + ((size_t)c << 18) + p0 + 4 * i));
    }
}

extern "C" void kernel_launch(void* const* d_in, const int* in_sizes, int n_in,
                              void* d_out, int out_size, void* d_ws, size_t ws_size,
                              hipStream_t stream) {
    const float* x   = (const float*)d_in[0];   // (B, N, C) f32
    const int*   idx = (const int*)  d_in[1];   // (B, N) int32
    float*       out = (float*)d_out;           // (B, C, NX, NY) f32

    int* head = (int*)d_ws;                     // [NBIN]
    int* nxt  = head + PFN_NBIN;                // [TOTPTS]

    // 1) head = -1 everywhere (ws is poisoned to 0xAA each launch)
    (void)hipMemsetAsync(head, 0xFF, (size_t)PFN_NBIN * sizeof(int), stream);
    // 2) chain points into per-bin linked lists (1 atomic/point)
    pfn_build<<<(PFN_TOTPTS + 255) / 256, 256, 0, stream>>>(idx, head, nxt);
    // 3) walk lists + transpose in LDS + single coalesced nontemporal write
    pfn_gather<<<PFN_NBIN / 64, 256, 0, stream>>>(x, head, nxt, out);
}